// Round 3
// baseline (10035.619 us; speedup 1.0000x reference)
//
#include <hip/hip_runtime.h>
#include <hip/hip_bf16.h>

#define BB 16
#define NN 1024
#define BN (BB*NN)
#define KK 20

// ============ cast pos -> double + row sqnorm ============
__global__ void k_cast3(const float* __restrict__ pos, double* __restrict__ xd,
                        double* __restrict__ sq) {
    int gn = blockIdx.x * blockDim.x + threadIdx.x;
    if (gn >= BN) return;
    double s = 0.0;
    #pragma unroll
    for (int c = 0; c < 3; ++c) {
        double v = (double)pos[gn * 3 + c];
        xd[gn * 3 + c] = v;
        s += v * v;
    }
    sq[gn] = s;
}

// ============ kNN in fp64 ============
// dist[m] = sq[n] + sq[m] - 2*dot; +1e10 diagonal; 20x argmin with masking,
// lowest-index tie-break. LDS kept well under 64KB (TM=32 for C=128).
template<int C, int TM>
__global__ void k_knn_d(const double* __restrict__ x, const double* __restrict__ sq,
                        int* __restrict__ idx) {
    const int ST = C + 1;                 // pad: kill power-of-2 bank conflicts
    __shared__ double xn[C];
    __shared__ double xt[TM * ST];
    __shared__ double d[NN];
    __shared__ double redv[4];
    __shared__ int    redi[4];
    const int n = blockIdx.x, b = blockIdx.y, tid = threadIdx.x;
    const double* xb = x + (size_t)b * NN * C;
    if (tid < C) xn[tid] = xb[(size_t)n * C + tid];
    __syncthreads();
    const double sqn = sq[b * NN + n];
    for (int m0 = 0; m0 < NN; m0 += TM) {
        for (int t = tid; t < TM * C; t += 256) {
            int r = t / C, c = t - r * C;
            xt[r * ST + c] = xb[(size_t)m0 * C + t];
        }
        __syncthreads();
        if (tid < TM) {
            const double* xr = &xt[tid * ST];
            double dot = 0.0;
            for (int c = 0; c < C; ++c) dot += xr[c] * xn[c];
            int m = m0 + tid;
            double dd = sqn + sq[b * NN + m] - 2.0 * dot;
            if (m == n) dd += 1e10;
            d[m] = dd;
        }
        __syncthreads();
    }
    for (int it = 0; it < KK; ++it) {
        double bv = 1e300; int bi = NN;
        for (int m = tid; m < NN; m += 256) {
            double v = d[m];
            if (v < bv) { bv = v; bi = m; }   // ascending m: keeps lowest index
        }
        for (int off = 32; off > 0; off >>= 1) {
            double ov = __shfl_xor(bv, off, 64);
            int    oi = __shfl_xor(bi, off, 64);
            if (ov < bv || (ov == bv && oi < bi)) { bv = ov; bi = oi; }
        }
        if ((tid & 63) == 0) { redv[tid >> 6] = bv; redi[tid >> 6] = bi; }
        __syncthreads();
        if (tid == 0) {
            double fv = redv[0]; int fi = redi[0];
            for (int w = 1; w < 4; ++w) {
                double ov = redv[w]; int oi = redi[w];
                if (ov < fv || (ov == fv && oi < fi)) { fv = ov; fi = oi; }
            }
            idx[(size_t)(b * NN + n) * KK + it] = fi;
            d[fi] = 1e300;
        }
        __syncthreads();
    }
}

// ============ UV GEMM fp64, 64-column chunk ============
// U = x@W_top + b ; V = x@(W_bot - W_top). Chunk cols [c0, c0+64).
template<int C>
__global__ void k_uv_d(const double* __restrict__ x, const float* __restrict__ W,
                       const float* __restrict__ bias,
                       double* __restrict__ U, double* __restrict__ V,
                       int Cout, int c0) {
    __shared__ double xt[16 * C];
    const int tid = threadIdx.x;
    const int col = tid & 63;
    const int gcol = c0 + col;
    const int r4 = tid >> 6;
    const int row0 = blockIdx.x * 16;
    for (int t = tid; t < 16 * C; t += 256) xt[t] = x[(size_t)row0 * C + t];
    __syncthreads();
    double u[4] = {0,0,0,0}, v[4] = {0,0,0,0};
    for (int c = 0; c < C; ++c) {
        double wt = (double)W[(size_t)c * Cout + gcol];
        double wd = (double)W[(size_t)(C + c) * Cout + gcol] - wt;
        #pragma unroll
        for (int rr = 0; rr < 4; ++rr) {
            double xv = xt[(r4 * 4 + rr) * C + c];
            u[rr] += xv * wt;
            v[rr] += xv * wd;
        }
    }
    double bb = (double)bias[gcol];
    #pragma unroll
    for (int rr = 0; rr < 4; ++rr) {
        size_t o = (size_t)(row0 + r4 * 4 + rr) * 64 + col;
        U[o] = u[rr] + bb;
        V[o] = v[rr];
    }
}

// ============ gather fp64: max/min over k + BN stats (blockDim = CS) ============
__global__ void k_gather_d(const int* __restrict__ idx,
                           double* __restrict__ U, const double* __restrict__ V,
                           double* __restrict__ Hmin,
                           double* __restrict__ ssum, double* __restrict__ sssq, int NB) {
    const int tid = threadIdx.x, CS = blockDim.x;
    __shared__ int lidx[KK];
    double accs = 0.0, accq = 0.0;
    const int gn0 = blockIdx.x * NB;
    for (int r = 0; r < NB; ++r) {
        int gn = gn0 + r;
        int b = gn >> 10;
        __syncthreads();
        if (tid < KK) lidx[tid] = idx[(size_t)gn * KK + tid];
        __syncthreads();
        double u = U[(size_t)gn * CS + tid];
        double vmax = -1e300, vmin = 1e300, vs = 0.0, vss = 0.0;
        for (int j = 0; j < KK; ++j) {
            int m = lidx[j];
            double vv = V[(size_t)((b << 10) + m) * CS + tid];
            vmax = fmax(vmax, vv);
            vmin = fmin(vmin, vv);
            vs  += vv;
            vss += vv * vv;
        }
        accs += (double)KK * u + vs;
        accq += (double)KK * u * u + 2.0 * u * vs + vss;
        U[(size_t)gn * CS + tid]    = u + vmax;
        Hmin[(size_t)gn * CS + tid] = u + vmin;
    }
    atomicAdd(&ssum[tid], accs);
    atomicAdd(&sssq[tid], accq);
}

// ============ BN finalize fp64 (64 channels: [c0, c0+64)) ============
__global__ void k_bnfin_d(const double* __restrict__ ssum, const double* __restrict__ sssq,
                          const float* __restrict__ g, const float* __restrict__ be,
                          double* __restrict__ S, double* __restrict__ T, int c0) {
    int gc = c0 + threadIdx.x;
    const double M = (double)BN * (double)KK;
    double mean = ssum[gc] / M;
    double var  = sssq[gc] / M - mean * mean;
    if (var < 0.0) var = 0.0;
    double s = (double)g[gc] / sqrt(var + 1e-5);
    double t = (double)be[gc] - mean * s;
    S[gc] = s; T[gc] = t;
}

// ============ apply fp64 chunk: y[:, c0:c0+64] = relu(s*h+t) ============
__global__ void k_apply_d(const double* __restrict__ Hmax, const double* __restrict__ Hmin,
                          const double* __restrict__ S, const double* __restrict__ T,
                          double* __restrict__ y, int Cout, int c0) {
    const int gn = blockIdx.x, tid = threadIdx.x;
    double s = S[c0 + tid], t = T[c0 + tid];
    double h = (s >= 0.0) ? Hmax[(size_t)gn * 64 + tid] : Hmin[(size_t)gn * 64 + tid];
    y[(size_t)gn * Cout + c0 + tid] = fmax(s * h + t, 0.0);
}

// ============ row sqnorm fp64: one 64-lane wave per row ============
__global__ void k_sqnorm_d(const double* __restrict__ y, double* __restrict__ sq, int C) {
    const int row = blockIdx.x * 4 + (threadIdx.x >> 6);
    const int lane = threadIdx.x & 63;
    const double* yr = y + (size_t)row * C;
    double s = 0.0;
    for (int c = lane; c < C; c += 64) { double v = yr[c]; s += v * v; }
    for (int off = 32; off > 0; off >>= 1) s += __shfl_xor(s, off, 64);
    if (lane == 0) sq[row] = s;
}

// ============ layer-4 fp32 path (C=128 -> Cout=1024, CS=128 chunks) ============
__global__ void k_uv_f(const double* __restrict__ x, const float* __restrict__ W,
                       const float* __restrict__ bias,
                       float* __restrict__ U, float* __restrict__ V, int c0) {
    __shared__ float xt[16 * 128];
    const int tid = threadIdx.x;
    const int col = blockIdx.x * 64 + (tid & 63);   // 0..127
    const int gcol = c0 + col;
    const int r4 = tid >> 6;
    const int row0 = blockIdx.y * 16;
    for (int t = tid; t < 16 * 128; t += 256) xt[t] = (float)x[(size_t)row0 * 128 + t];
    __syncthreads();
    float u[4] = {0,0,0,0}, v[4] = {0,0,0,0};
    for (int c = 0; c < 128; ++c) {
        float wt = W[(size_t)c * 1024 + gcol];
        float wd = W[(size_t)(128 + c) * 1024 + gcol] - wt;
        #pragma unroll
        for (int rr = 0; rr < 4; ++rr) {
            float xv = xt[(r4 * 4 + rr) * 128 + c];
            u[rr] += xv * wt;
            v[rr] += xv * wd;
        }
    }
    float bb = bias[gcol];
    #pragma unroll
    for (int rr = 0; rr < 4; ++rr) {
        size_t o = (size_t)(row0 + r4 * 4 + rr) * 128 + col;
        U[o] = u[rr] + bb;
        V[o] = v[rr];
    }
}

__global__ void k_gather_f(const int* __restrict__ idx,
                           float* __restrict__ U, const float* __restrict__ V,
                           float* __restrict__ Hmin,
                           double* __restrict__ ssum, double* __restrict__ sssq, int NB) {
    const int tid = threadIdx.x, CS = blockDim.x;
    __shared__ int lidx[KK];
    double accs = 0.0, accq = 0.0;
    const int gn0 = blockIdx.x * NB;
    for (int r = 0; r < NB; ++r) {
        int gn = gn0 + r;
        int b = gn >> 10;
        __syncthreads();
        if (tid < KK) lidx[tid] = idx[(size_t)gn * KK + tid];
        __syncthreads();
        float u = U[(size_t)gn * CS + tid];
        float vmax = -3e38f, vmin = 3e38f, vs = 0.f, vss = 0.f;
        for (int j = 0; j < KK; ++j) {
            int m = lidx[j];
            float vv = V[(size_t)((b << 10) + m) * CS + tid];
            vmax = fmaxf(vmax, vv);
            vmin = fminf(vmin, vv);
            vs  += vv;
            vss += vv * vv;
        }
        accs += (double)((float)KK * u + vs);
        accq += (double)((float)KK * u * u + 2.f * u * vs + vss);
        U[(size_t)gn * CS + tid]    = u + vmax;
        Hmin[(size_t)gn * CS + tid] = u + vmin;
    }
    atomicAdd(&ssum[tid], accs);
    atomicAdd(&sssq[tid], accq);
}

__global__ void k_bnfin_f(const double* __restrict__ ssum, const double* __restrict__ sssq,
                          const float* __restrict__ g, const float* __restrict__ be,
                          float* __restrict__ S, float* __restrict__ T, int c0) {
    int gc = c0 + blockIdx.x * 64 + threadIdx.x;
    const double M = (double)BN * (double)KK;
    double mean = ssum[gc] / M;
    double var  = sssq[gc] / M - mean * mean;
    if (var < 0.0) var = 0.0;
    float s = (float)((double)g[gc] / sqrt(var + 1e-5));
    float t = (float)((double)be[gc] - mean * (double)s);
    S[gc] = s; T[gc] = t;
}

__global__ void k_applymax(const float* __restrict__ Hmax, const float* __restrict__ Hmin,
                           const float* __restrict__ S, const float* __restrict__ T,
                           float* __restrict__ z, int c0) {
    const int col = blockIdx.x * 64 + (threadIdx.x & 63);   // 0..127
    const int nl  = threadIdx.x >> 6;
    const int b   = blockIdx.y;
    float s = S[c0 + col], t = T[c0 + col];
    bool pos = (s >= 0.f);
    float e = pos ? -3e38f : 3e38f;
    for (int n = nl; n < NN; n += 4) {
        size_t o = (size_t)(b * NN + n) * 128 + col;
        float h = pos ? Hmax[o] : Hmin[o];
        e = pos ? fmaxf(e, h) : fminf(e, h);
    }
    __shared__ float red[256];
    red[threadIdx.x] = e;
    __syncthreads();
    if (nl == 0) {
        float e0 = red[threadIdx.x], e1 = red[64 + threadIdx.x],
              e2 = red[128 + threadIdx.x], e3 = red[192 + threadIdx.x];
        float ee = pos ? fmaxf(fmaxf(e0, e1), fmaxf(e2, e3))
                       : fminf(fminf(e0, e1), fminf(e2, e3));
        z[(size_t)b * 1024 + c0 + col] = fmaxf(s * ee + t, 0.f);
    }
}

// ============ FC head ============
__global__ void k_fc1(const float* __restrict__ z, const float* __restrict__ Wc1,
                      const float* __restrict__ bc1, float* __restrict__ a1) {
    int j = blockIdx.x * blockDim.x + threadIdx.x;
    if (j >= BB * 512) return;
    int b = j >> 9, jj = j & 511;
    const float* zr = z + (size_t)b * 1024;
    float acc = bc1[jj];
    for (int c = 0; c < 1024; ++c) acc += zr[c] * Wc1[(size_t)c * 512 + jj];
    a1[j] = fmaxf(acc, 0.f);
}

__global__ void k_fc2(const float* __restrict__ a1, const float* __restrict__ Wc2,
                      const float* __restrict__ bc2, float* __restrict__ out) {
    int j = blockIdx.x * blockDim.x + threadIdx.x;
    if (j >= BB * 40) return;
    int b = j / 40, jj = j % 40;
    const float* ar = a1 + (size_t)b * 512;
    float acc = bc2[jj];
    for (int c = 0; c < 512; ++c) acc += ar[c] * Wc2[(size_t)c * 40 + jj];
    out[j] = acc;
}

extern "C" void kernel_launch(void* const* d_in, const int* in_sizes, int n_in,
                              void* d_out, int out_size, void* d_ws, size_t ws_size,
                              hipStream_t stream) {
    const float* pos = (const float*)d_in[0];
    const float* Wc1 = (const float*)d_in[17];
    const float* bc1 = (const float*)d_in[18];
    const float* Wc2 = (const float*)d_in[19];
    const float* bc2 = (const float*)d_in[20];

    char* p = (char*)d_ws;
    auto alloc = [&](size_t bytes) -> void* {
        void* r = (void*)p;
        p += (bytes + 255) & ~(size_t)255;
        return r;
    };
    // scratch unions: 8MB each = BN x 64 fp64  OR  BN x 128 fp32
    void*   bufA = alloc((size_t)BN * 64 * 8);
    void*   bufB = alloc((size_t)BN * 64 * 8);
    void*   bufC = alloc((size_t)BN * 64 * 8);
    double* Ya   = (double*)alloc((size_t)BN * 64 * 8);    // L1/L2 output (64-wide)
    double* Yb   = (double*)alloc((size_t)BN * 128 * 8);   // L3 output (128-wide)
    double* Xd   = (double*)alloc((size_t)BN * 3 * 8);
    double* SQd  = (double*)alloc((size_t)BN * 8);
    int*    IDX  = (int*)   alloc((size_t)BN * KK * 4);
    double* SSUM = (double*)alloc((size_t)4096 * 8);
    double* SSSQ = (double*)alloc((size_t)4096 * 8);
    double* Sd   = (double*)alloc((size_t)128 * 8);
    double* Td   = (double*)alloc((size_t)128 * 8);
    float*  Sf   = (float*) alloc((size_t)1024 * 4);
    float*  Tf   = (float*) alloc((size_t)1024 * 4);
    float*  Z    = (float*) alloc((size_t)BB * 1024 * 4);
    float*  A1   = (float*) alloc((size_t)BB * 512 * 4);
    // total ~= 50 MB

    double* Ud = (double*)bufA; double* Vd = (double*)bufB; double* Hd = (double*)bufC;
    float*  Uf = (float*)bufA;  float*  Vf = (float*)bufB;  float*  Hf = (float*)bufC;

    hipMemsetAsync(SSUM, 0, 4096 * 8 * 2, stream);

    k_cast3<<<(BN + 255) / 256, 256, 0, stream>>>(pos, Xd, SQd);

    // ---- Layer 1: C=3 -> 64 ----
    {
        const float* W = (const float*)d_in[1], *bs = (const float*)d_in[2];
        const float* g = (const float*)d_in[3], *be = (const float*)d_in[4];
        k_knn_d<3, 64><<<dim3(NN, BB), 256, 0, stream>>>(Xd, SQd, IDX);
        k_uv_d<3><<<BN / 16, 256, 0, stream>>>(Xd, W, bs, Ud, Vd, 64, 0);
        k_gather_d<<<BN / 8, 64, 0, stream>>>(IDX, Ud, Vd, Hd, SSUM, SSSQ, 8);
        k_bnfin_d<<<1, 64, 0, stream>>>(SSUM, SSSQ, g, be, Sd, Td, 0);
        k_apply_d<<<BN, 64, 0, stream>>>(Ud, Hd, Sd, Td, Ya, 64, 0);
        k_sqnorm_d<<<BN / 4, 256, 0, stream>>>(Ya, SQd, 64);
    }
    // ---- Layer 2: C=64 -> 64 (in-place on Ya is safe: single chunk, stream order) ----
    {
        const float* W = (const float*)d_in[5], *bs = (const float*)d_in[6];
        const float* g = (const float*)d_in[7], *be = (const float*)d_in[8];
        k_knn_d<64, 64><<<dim3(NN, BB), 256, 0, stream>>>(Ya, SQd, IDX);
        k_uv_d<64><<<BN / 16, 256, 0, stream>>>(Ya, W, bs, Ud, Vd, 64, 0);
        k_gather_d<<<BN / 8, 64, 0, stream>>>(IDX, Ud, Vd, Hd, SSUM + 1024, SSSQ + 1024, 8);
        k_bnfin_d<<<1, 64, 0, stream>>>(SSUM + 1024, SSSQ + 1024, g, be, Sd, Td, 0);
        k_apply_d<<<BN, 64, 0, stream>>>(Ud, Hd, Sd, Td, Ya, 64, 0);
        k_sqnorm_d<<<BN / 4, 256, 0, stream>>>(Ya, SQd, 64);
    }
    // ---- Layer 3: C=64 -> 128, two 64-col chunks, Ya -> Yb (NOT in place) ----
    {
        const float* W = (const float*)d_in[9], *bs = (const float*)d_in[10];
        const float* g = (const float*)d_in[11], *be = (const float*)d_in[12];
        k_knn_d<64, 64><<<dim3(NN, BB), 256, 0, stream>>>(Ya, SQd, IDX);
        for (int cc = 0; cc < 2; ++cc) {
            const int c0 = cc * 64;
            k_uv_d<64><<<BN / 16, 256, 0, stream>>>(Ya, W, bs, Ud, Vd, 128, c0);
            k_gather_d<<<BN / 8, 64, 0, stream>>>(IDX, Ud, Vd, Hd,
                                                  SSUM + 2048 + c0, SSSQ + 2048 + c0, 8);
            k_bnfin_d<<<1, 64, 0, stream>>>(SSUM + 2048, SSSQ + 2048, g, be, Sd, Td, c0);
            k_apply_d<<<BN, 64, 0, stream>>>(Ud, Hd, Sd, Td, Yb, 128, c0);
        }
        k_sqnorm_d<<<BN / 4, 256, 0, stream>>>(Yb, SQd, 128);
    }
    // ---- Layer 4: C=128 -> 1024, fp32, eight 128-col chunks ----
    {
        const float* W = (const float*)d_in[13], *bs = (const float*)d_in[14];
        const float* g = (const float*)d_in[15], *be = (const float*)d_in[16];
        k_knn_d<128, 32><<<dim3(NN, BB), 256, 0, stream>>>(Yb, SQd, IDX);
        for (int cc = 0; cc < 8; ++cc) {
            const int c0 = cc * 128;
            k_uv_f<<<dim3(2, BN / 16), 256, 0, stream>>>(Yb, W, bs, Uf, Vf, c0);
            k_gather_f<<<BN / 8, 128, 0, stream>>>(IDX, Uf, Vf, Hf,
                                                   SSUM + 3072 + c0, SSSQ + 3072 + c0, 8);
            k_bnfin_f<<<2, 64, 0, stream>>>(SSUM + 3072, SSSQ + 3072, g, be, Sf, Tf, c0);
            k_applymax<<<dim3(2, BB), 256, 0, stream>>>(Uf, Hf, Sf, Tf, Z, c0);
        }
    }

    k_fc1<<<(BB * 512 + 255) / 256, 256, 0, stream>>>(Z, Wc1, bc1, A1);
    k_fc2<<<(BB * 40 + 255) / 256, 256, 0, stream>>>(A1, Wc2, bc2, (float*)d_out);
}